// Round 5
// baseline (1886.243 us; speedup 1.0000x reference)
//
#include <hip/hip_runtime.h>

// GRU via token->gi table:
//   A) f32->bf16 converts (W_hh prescaled by log2e / 2log2e per gate group).
//   B) tbl[v][g] = scale_g*(W_ih@emb[v] + b_ih + (g<512? b_hh:0)), bf16, 49 MB.
//   C) gru_rec: 32 blocks x 512 thr, 512 steps, single launch. W_hh register-resident;
//      per step gather 16 table rows via REGISTER staging (3x global_load_dwordx4 per
//      wave, issued 2 steps ahead; vmcnt(3) + swizzled ds_write_b128 late in step);
//      exp2-domain gates; parity-2 unrolled, one barrier per step.

typedef unsigned short ushort_t;
typedef __attribute__((ext_vector_type(8))) short short8;
typedef __attribute__((ext_vector_type(4))) float float4_;
typedef __attribute__((ext_vector_type(4))) unsigned short ushort4_;
typedef __attribute__((ext_vector_type(2))) unsigned int uint2_;
typedef __attribute__((ext_vector_type(4))) int int4_;

#define VOCAB 32000
#define EMB 128
#define HID 256
#define G3 768
#define TT 512
#define L2E 1.4426950408889634f
#define L2E2 2.8853900817779268f
#define HBASE 49152
#define XBASE 65536

__device__ __forceinline__ ushort_t f2b(float f) {
  unsigned u = __float_as_uint(f);
  return (ushort_t)((u + 0x7FFFu + ((u >> 16) & 1u)) >> 16);
}
__device__ __forceinline__ short8 ld8(const ushort_t* p) { return *(const short8*)p; }
__device__ __forceinline__ float exp2f_raw(float x) {
  float r; asm("v_exp_f32 %0, %1" : "=v"(r) : "v"(x)); return r;
}
__device__ __forceinline__ unsigned pkbf(float a, float b) {
  unsigned r; asm("v_cvt_pk_bf16_f32 %0, %1, %2" : "=v"(r) : "v"(a), "v"(b));
  return r;
}

// ---------------- Phase A ----------------
__global__ void cvt_bf16_k(const float* __restrict__ s, ushort_t* __restrict__ d, int n4) {
  int i = blockIdx.x * blockDim.x + threadIdx.x;
  int stride = gridDim.x * blockDim.x;
  for (; i < n4; i += stride) {
    float4_ v = ((const float4_*)s)[i];
    ushort4_ o;
    o.x = f2b(v.x); o.y = f2b(v.y); o.z = f2b(v.z); o.w = f2b(v.w);
    ((ushort4_*)d)[i] = o;
  }
}
__global__ void cvt_whh_k(const float* __restrict__ s, ushort_t* __restrict__ d) {
  int i = blockIdx.x * blockDim.x + threadIdx.x;
  if (i >= (G3 * HID) / 4) return;
  float sc = ((i >> 6) < 512) ? L2E : L2E2;
  float4_ v = ((const float4_*)s)[i];
  ushort4_ o;
  o.x = f2b(v.x * sc); o.y = f2b(v.y * sc); o.z = f2b(v.z * sc); o.w = f2b(v.w * sc);
  ((ushort4_*)d)[i] = o;
}

// ---------------- Phase B: token->gi table (2000 blocks) ----------------
__global__ __launch_bounds__(256) void tbl_gemm(
    const ushort_t* __restrict__ emb16, const ushort_t* __restrict__ Wih16,
    const float* __restrict__ bih, const float* __restrict__ bhh,
    char* __restrict__ tb_out) {
  __shared__ float cbs[G3];
  __shared__ alignas(16) char img[16 * 1552];
  const int tid = threadIdx.x;
  for (int i = tid; i < G3; i += 256) {
    float sc = (i < 512) ? L2E : L2E2;
    cbs[i] = sc * (bih[i] + (i < 512 ? bhh[i] : 0.f));
  }
  const int lane = tid & 63, w = tid >> 6;
  const int bl = lane & 15, kg = lane >> 4;
  const int v0 = blockIdx.x * 16;

  short8 bfr[4];
#pragma unroll
  for (int kt = 0; kt < 4; ++kt)
    bfr[kt] = ld8(emb16 + (size_t)(v0 + bl) * EMB + kt * 32 + kg * 8);
  __syncthreads();

#pragma unroll 1
  for (int mi = 0; mi < 12; ++mi) {
    int mt = w * 12 + mi;
    short8 af[4];
#pragma unroll
    for (int kt = 0; kt < 4; ++kt)
      af[kt] = ld8(Wih16 + (mt * 16 + bl) * EMB + kt * 32 + kg * 8);
    float4_ acc = {0.f, 0.f, 0.f, 0.f};
#pragma unroll
    for (int kt = 0; kt < 4; ++kt)
      acc = __builtin_amdgcn_mfma_f32_16x16x32_bf16(af[kt], bfr[kt], acc, 0, 0, 0);
    float sc = (mt < 32) ? L2E : L2E2;
    int g0 = mt * 16 + kg * 4;
    float a0 = fmaf(sc, acc[0], cbs[g0 + 0]);
    float a1 = fmaf(sc, acc[1], cbs[g0 + 1]);
    float a2 = fmaf(sc, acc[2], cbs[g0 + 2]);
    float a3 = fmaf(sc, acc[3], cbs[g0 + 3]);
    uint2_ o;
    o.x = pkbf(a0, a1);
    o.y = pkbf(a2, a3);
    *(uint2_*)(img + bl * 1552 + mt * 32 + kg * 8) = o;
  }
  __syncthreads();

#pragma unroll
  for (int c = 0; c < 6; ++c) {
    int p = c * 4096 + tid * 16;
    int q = p >> 9;
    int row = (q * 21846) >> 16;  // q/3
    int off = p - row * 1536;
    float4_ v = *(const float4_*)(img + row * 1552 + off);
    *(float4_*)(tb_out + (size_t)(v0 + row) * 1536 + off) = v;
  }
}

// ---------------- Phase C: recurrence ----------------
// LDS: gi[2][24576] @0 | h[2][8192] @49152 | x[16*512] int @65536  = 98304 B
__global__ __launch_bounds__(512, 2) void gru_rec(
    const ushort_t* __restrict__ Whh16, const char* __restrict__ tbl,
    const float* __restrict__ bhh, const int* __restrict__ x,
    float* __restrict__ out) {
  __shared__ alignas(16) char smem[98304];

  const int tid = threadIdx.x, lane = tid & 63, w = tid >> 6;
  const int bl = lane & 15, kg = lane >> 4;
  const int b0 = blockIdx.x * 16;
  const int s16 = (bl & 7) << 4;

  // stage x (16 rows x 512 int) and zero h[0]
  {
    const int4_* xs = (const int4_*)(x + (size_t)b0 * TT);
    int4_* xd = (int4_*)(smem + XBASE);
#pragma unroll
    for (int i = 0; i < 4; ++i) xd[tid + i * 512] = xs[tid + i * 512];
    int4_ z4 = {0, 0, 0, 0};
    *(int4_*)(smem + HBASE + tid * 16) = z4;
  }
  __syncthreads();

  // W_hh fragments (prescaled), register/AGPR-resident
  short8 wf[2][3][8];
#pragma unroll
  for (int i = 0; i < 2; ++i)
#pragma unroll
    for (int q = 0; q < 3; ++q) {
      int g = (w + 8 * i + 16 * q) * 16 + bl;
#pragma unroll
      for (int kt = 0; kt < 8; ++kt)
        wf[i][q][kt] = ld8(Whh16 + (size_t)g * HID + kt * 32 + kg * 8);
    }

  // loop-invariant LDS byte offsets
  int h_off[8], gi_off[2][2], gn_off[2], hw_off[2];
#pragma unroll
  for (int kt = 0; kt < 8; ++kt)
    h_off[kt] = HBASE + ((bl * 512 + kt * 64 + kg * 16) ^ s16);
#pragma unroll
  for (int i = 0; i < 2; ++i) {
#pragma unroll
    for (int q = 0; q < 2; ++q)
      gi_off[i][q] = (bl * 1536 + 32 * (w + 8 * i + 16 * q) + 8 * kg) ^ s16;
    gn_off[i] = (bl * 1536 + 32 * (32 + w + 8 * i) + 8 * kg) ^ s16;
    hw_off[i] = HBASE + ((bl * 512 + ((w + 8 * i) * 16 + kg * 4) * 2) ^ s16);
  }

  // gather staging invariants: wave w owns batch-local rows 2w (lanes<32), 2w+1
  const int row = 2 * w + (lane >> 5);
  const int colb = (lane & 31) * 16;
  const int xrow = XBASE + row * 2048;
  const int rsw = (row & 7) << 4;
  const int dst0 = (row * 1536 + colb) ^ rsw;
  const int dst1 = (row * 1536 + 512 + colb) ^ rsw;
  const int dst2 = (row * 1536 + 1024 + colb) ^ rsw;

  float4_ bhn[2];
  float hreg[2][4];
#pragma unroll
  for (int i = 0; i < 2; ++i) {
    float4_ bv = *(const float4_*)&bhh[512 + (w + 8 * i) * 16 + kg * 4];
#pragma unroll
    for (int r = 0; r < 4; ++r) { bhn[i][r] = L2E2 * bv[r]; hreg[i][r] = 0.f; }
  }

  // prologue: load sets 0,1 into regs; write set0 -> tile0
  float4_ g0[3], g1[3];
  {
    int tok0 = *(const int*)(smem + xrow);
    int tok1 = *(const int*)(smem + xrow + 4);
    const char* s0p = (const char*)tbl + (unsigned)tok0 * 1536u + colb;
    const char* s1p = (const char*)tbl + (unsigned)tok1 * 1536u + colb;
    g0[0] = *(const float4_*)(s0p);
    g0[1] = *(const float4_*)(s0p + 512);
    g0[2] = *(const float4_*)(s0p + 1024);
    g1[0] = *(const float4_*)(s1p);
    g1[1] = *(const float4_*)(s1p + 512);
    g1[2] = *(const float4_*)(s1p + 1024);
    asm volatile("s_waitcnt vmcnt(3)" ::: "memory");
    *(float4_*)(smem + dst0) = g0[0];
    *(float4_*)(smem + dst1) = g0[1];
    *(float4_*)(smem + dst2) = g0[2];
  }
  asm volatile("s_waitcnt lgkmcnt(0)" ::: "memory");
  __builtin_amdgcn_s_barrier();
  __builtin_amdgcn_sched_barrier(0);

  // Per step t (parity PAR): read gi tile[PAR] + h[PAR]; issue loads for t+2 into
  // g[PAR]; write set t+1 (g[NPAR]) into tile[NPAR] after vmcnt; h_{t+1} -> h[NPAR].
#define STEP(PAR, NPAR, TT2, DO_ISSUE, DO_WRITE, WN) do { \
    if (DO_ISSUE) { \
      int tok = *(const int*)(smem + xrow + 4 * (TT2)); \
      const char* sp = (const char*)tbl + (unsigned)tok * 1536u + colb; \
      g##PAR[0] = *(const float4_*)(sp); \
      g##PAR[1] = *(const float4_*)(sp + 512); \
      g##PAR[2] = *(const float4_*)(sp + 1024); \
    } \
    float4_ acc[2][3]; \
    _Pragma("unroll") for (int i = 0; i < 2; ++i) { \
      _Pragma("unroll") for (int q = 0; q < 2; ++q) { \
        uint2_ dg = *(const uint2_*)(smem + (PAR) * 24576 + gi_off[i][q]); \
        acc[i][q][0] = __uint_as_float(dg.x << 16); \
        acc[i][q][1] = __uint_as_float(dg.x & 0xFFFF0000u); \
        acc[i][q][2] = __uint_as_float(dg.y << 16); \
        acc[i][q][3] = __uint_as_float(dg.y & 0xFFFF0000u); \
      } \
      acc[i][2] = bhn[i]; \
    } \
    _Pragma("unroll") for (int kt = 0; kt < 8; ++kt) { \
      short8 bf = *(const short8*)(smem + h_off[kt] + (PAR) * 8192); \
      _Pragma("unroll") for (int i = 0; i < 2; ++i) \
        _Pragma("unroll") for (int q = 0; q < 3; ++q) \
          acc[i][q] = __builtin_amdgcn_mfma_f32_16x16x32_bf16(wf[i][q][kt], bf, acc[i][q], 0, 0, 0); \
    } \
    _Pragma("unroll") for (int i = 0; i < 2; ++i) { \
      uint2_ gd = *(const uint2_*)(smem + (PAR) * 24576 + gn_off[i]); \
      float gn0 = __uint_as_float(gd.x << 16); \
      float gn1 = __uint_as_float(gd.x & 0xFFFF0000u); \
      float gn2 = __uint_as_float(gd.y << 16); \
      float gn3 = __uint_as_float(gd.y & 0xFFFF0000u); \
      _Pragma("unroll") for (int r = 0; r < 4; ++r) { \
        float gnr = (r == 0) ? gn0 : (r == 1) ? gn1 : (r == 2) ? gn2 : gn3; \
        float rr = __builtin_amdgcn_rcpf(1.f + exp2f_raw(-acc[i][0][r])); \
        float zz = __builtin_amdgcn_rcpf(1.f + exp2f_raw(-acc[i][1][r])); \
        float y = fmaf(rr, acc[i][2][r], gnr); \
        float nn = fmaf(-2.f, __builtin_amdgcn_rcpf(1.f + exp2f_raw(y)), 1.f); \
        hreg[i][r] = fmaf(zz, hreg[i][r] - nn, nn); \
      } \
      uint2_ hv; \
      hv.x = pkbf(hreg[i][0], hreg[i][1]); \
      hv.y = pkbf(hreg[i][2], hreg[i][3]); \
      *(uint2_*)(smem + hw_off[i] + (NPAR) * 8192) = hv; \
    } \
    if (DO_WRITE) { \
      asm volatile("s_waitcnt vmcnt(" #WN ")" ::: "memory"); \
      char* dp = smem + (NPAR) * 24576; \
      *(float4_*)(dp + dst0) = g##NPAR[0]; \
      *(float4_*)(dp + dst1) = g##NPAR[1]; \
      *(float4_*)(dp + dst2) = g##NPAR[2]; \
    } \
    asm volatile("s_waitcnt lgkmcnt(0)" ::: "memory"); \
    __builtin_amdgcn_s_barrier(); \
    __builtin_amdgcn_sched_barrier(0); \
  } while (0)

#pragma unroll 1
  for (int t = 0; t < 510; t += 2) {
    STEP(0, 1, t + 2, 1, 1, 3);
    STEP(1, 0, t + 3, 1, 1, 3);
  }
  STEP(0, 1, 0, 0, 1, 0);  // t = 510: no issue; drain + write set 511
  STEP(1, 0, 0, 0, 0, 0);  // t = 511: pure compute
#undef STEP

#pragma unroll
  for (int i = 0; i < 2; ++i) {
    float4_ v = {hreg[i][0], hreg[i][1], hreg[i][2], hreg[i][3]};
    *(float4_*)&out[(size_t)(b0 + bl) * HID + (w + 8 * i) * 16 + kg * 4] = v;
  }
}

extern "C" void kernel_launch(void* const* d_in, const int* in_sizes, int n_in,
                              void* d_out, int out_size, void* d_ws, size_t ws_size,
                              hipStream_t stream) {
  const int* x = (const int*)d_in[0];
  const float* emb = (const float*)d_in[1];
  const float* Wih = (const float*)d_in[2];
  const float* Whh = (const float*)d_in[3];
  const float* bih = (const float*)d_in[4];
  const float* bhh = (const float*)d_in[5];
  float* out = (float*)d_out;

  char* ws = (char*)d_ws;
  ushort_t* emb16 = (ushort_t*)ws;                 // 8,192,000 B
  ushort_t* Wih16 = (ushort_t*)(ws + 8192000);     //   196,608 B
  ushort_t* Whh16 = (ushort_t*)(ws + 8388608);     //   393,216 B (prescaled)
  char* tbl = ws + 8781824;                        // 49,152,000 B token->gi table

  cvt_bf16_k<<<1024, 256, 0, stream>>>(emb, emb16, (VOCAB * EMB) / 4);
  cvt_bf16_k<<<96, 256, 0, stream>>>(Wih, Wih16, (G3 * EMB) / 4);
  cvt_whh_k<<<192, 256, 0, stream>>>(Whh, Whh16);
  tbl_gemm<<<2000, 256, 0, stream>>>(emb16, Wih16, bih, bhh, tbl);
  gru_rec<<<32, 512, 0, stream>>>(Whh16, tbl, bhh, x, out);
}

// Round 6
// 1360.859 us; speedup vs baseline: 1.3861x; 1.3861x over previous
//
#include <hip/hip_runtime.h>

// GRU via token->gi table, R3-proven recurrence body:
//   A) f32->bf16 converts (natural domain, no prescale).
//   B) tbl[v][g] = W_ih@emb[v] + b_ih + (g<512 ? b_hh : 0), bf16 row-major [v][768], 49 MB.
//   C) gru_rec: single launch, 32 blocks x 512 thr, 512 steps. W_hh register-resident;
//      4-deep gi LDS ring; per step each wave stages 2 table rows via 3x global_load_lds
//      (inverse-swizzled per-lane SOURCE, linear LDS dest); counted vmcnt(6/3/0);
//      one barrier per step; R3's exact gate math.

typedef unsigned short ushort_t;
typedef __attribute__((ext_vector_type(8))) short short8;
typedef __attribute__((ext_vector_type(4))) float float4_;
typedef __attribute__((ext_vector_type(4))) unsigned short ushort4_;
typedef __attribute__((ext_vector_type(2))) unsigned int uint2_;
typedef __attribute__((ext_vector_type(4))) int int4_;

#define VOCAB 32000
#define EMB 128
#define HID 256
#define G3 768
#define TT 512
#define HB 98304   // h double-buffer base in smem
#define XB 114688  // x token slice base in smem

__device__ __forceinline__ float b2f(ushort_t u) {
  return __uint_as_float(((unsigned)u) << 16);
}
__device__ __forceinline__ ushort_t f2b(float f) {
  unsigned u = __float_as_uint(f);
  return (ushort_t)((u + 0x7FFFu + ((u >> 16) & 1u)) >> 16);
}
__device__ __forceinline__ short8 ld8(const ushort_t* p) { return *(const short8*)p; }
__device__ __forceinline__ void gld_lds16(const void* g, void* l) {
  __builtin_amdgcn_global_load_lds((const __attribute__((address_space(1))) void*)g,
                                   (__attribute__((address_space(3))) void*)l, 16, 0, 0);
}
// swizzled byte offset of (batch-local bl, byte-col c) inside a 24576-B tile
__device__ __forceinline__ int gi_byte(int bl, int c) {
  return ((bl * 1536) + c) ^ ((bl & 7) << 4);
}

// ---------------- Phase A ----------------
__global__ void cvt_bf16_k(const float* __restrict__ s, ushort_t* __restrict__ d, int n4) {
  int i = blockIdx.x * blockDim.x + threadIdx.x;
  int stride = gridDim.x * blockDim.x;
  for (; i < n4; i += stride) {
    float4_ v = ((const float4_*)s)[i];
    ushort4_ o;
    o.x = f2b(v.x); o.y = f2b(v.y); o.z = f2b(v.z); o.w = f2b(v.w);
    ((ushort4_*)d)[i] = o;
  }
}

// ---------------- Phase B: token->gi table (2000 blocks x 256 thr) ----------------
__global__ __launch_bounds__(256) void tbl_gemm(
    const ushort_t* __restrict__ emb16, const ushort_t* __restrict__ Wih16,
    const float* __restrict__ bih, const float* __restrict__ bhh,
    char* __restrict__ tb_out) {
  __shared__ float cbs[G3];
  __shared__ alignas(16) char img[16 * 1552];
  const int tid = threadIdx.x;
  for (int i = tid; i < G3; i += 256) cbs[i] = bih[i] + (i < 512 ? bhh[i] : 0.f);
  const int lane = tid & 63, w = tid >> 6;
  const int bl = lane & 15, kg = lane >> 4;
  const int v0 = blockIdx.x * 16;

  short8 bfr[4];
#pragma unroll
  for (int kt = 0; kt < 4; ++kt)
    bfr[kt] = ld8(emb16 + (size_t)(v0 + bl) * EMB + kt * 32 + kg * 8);
  __syncthreads();

#pragma unroll 1
  for (int mi = 0; mi < 12; ++mi) {
    int mt = w * 12 + mi;
    short8 af[4];
#pragma unroll
    for (int kt = 0; kt < 4; ++kt)
      af[kt] = ld8(Wih16 + (mt * 16 + bl) * EMB + kt * 32 + kg * 8);
    float4_ acc = {0.f, 0.f, 0.f, 0.f};
#pragma unroll
    for (int kt = 0; kt < 4; ++kt)
      acc = __builtin_amdgcn_mfma_f32_16x16x32_bf16(af[kt], bfr[kt], acc, 0, 0, 0);
    int g0 = mt * 16 + kg * 4;
    ushort4_ o;
#pragma unroll
    for (int r = 0; r < 4; ++r) o[r] = f2b(acc[r] + cbs[g0 + r]);
    *(ushort4_*)(img + bl * 1552 + mt * 32 + kg * 8) = o;
  }
  __syncthreads();

#pragma unroll
  for (int c = 0; c < 6; ++c) {
    int p = c * 4096 + tid * 16;
    int q = p >> 9;
    int row = (q * 21846) >> 16;  // q/3 for q<48
    int off = p - row * 1536;
    float4_ v = *(const float4_*)(img + row * 1552 + off);
    *(float4_*)(tb_out + (size_t)(v0 + row) * 1536 + off) = v;
  }
}

// ---------------- Phase C: recurrence ----------------
// LDS: ring[4][24576] @0 | h[2][8192] @98304 | x[16*512] int @114688 = 147456 B
__global__ __launch_bounds__(512, 2) void gru_rec(
    const ushort_t* __restrict__ Whh16, const char* __restrict__ tbl,
    const float* __restrict__ bhh, const int* __restrict__ x,
    float* __restrict__ out) {
  __shared__ alignas(16) char smem[147456];

  const int tid = threadIdx.x, lane = tid & 63, w = tid >> 6;
  const int bl = lane & 15, kg = lane >> 4;
  const int b0 = blockIdx.x * 16;

  // stage x slice (16 rows x 512 int) and zero h[0]
  {
    const int4_* xs = (const int4_*)(x + (size_t)b0 * TT);
    int4_* xd = (int4_*)(smem + XB);
#pragma unroll
    for (int i = 0; i < 4; ++i) xd[tid + i * 512] = xs[tid + i * 512];
    int4_ z4 = {0, 0, 0, 0};
    *(int4_*)(smem + HB + tid * 16) = z4;
  }
  __syncthreads();  // x and h[0] visible

  // W_hh fragments, register/AGPR-resident for all steps.
  short8 wf[2][3][8];
#pragma unroll
  for (int i = 0; i < 2; ++i)
#pragma unroll
    for (int q = 0; q < 3; ++q) {
      int g = (w + 8 * i + 16 * q) * 16 + bl;
#pragma unroll
      for (int kt = 0; kt < 8; ++kt)
        wf[i][q][kt] = ld8(Whh16 + (size_t)g * HID + kt * 32 + kg * 8);
    }

  float4_ bhn[2];
  float hreg[2][4];
#pragma unroll
  for (int i = 0; i < 2; ++i) {
    bhn[i] = *(const float4_*)&bhh[512 + (w + 8 * i) * 16 + kg * 4];
#pragma unroll
    for (int r = 0; r < 4; ++r) hreg[i][r] = 0.f;
  }

  // gather-source swizzle constants (wave w stages batch-local rows 2w, 2w+1)
  const int s0 = ((2 * w) & 7) << 4, s1 = ((2 * w + 1) & 7) << 4;
  const unsigned inv0 = (unsigned)((lane * 16) ^ s0);
  const unsigned inv1 = (lane < 32) ? (unsigned)((1024 + lane * 16) ^ s0)
                                    : (unsigned)((lane * 16 - 512) ^ s1);
  const unsigned inv2 = (unsigned)((512 + lane * 16) ^ s1);
  const int* xtA = (const int*)(smem + XB) + (2 * w) * TT;
  const int* xtB = (const int*)(smem + XB) + (2 * w + 1) * TT;

  // drain wf/bhn loads so in-loop vmcnt counts only ring loads
  asm volatile("s_waitcnt vmcnt(0)" ::: "memory");

  // prologue: stage slots 0..2
#pragma unroll
  for (int tau = 0; tau < 3; ++tau) {
    int tokA = xtA[tau], tokB = xtB[tau];
    const char* pA = tbl + (unsigned)tokA * 1536u;
    const char* pB = tbl + (unsigned)tokB * 1536u;
    const char* pM = (lane < 32) ? pA : pB;
    char* d0 = smem + tau * 24576 + w * 3072;
    gld_lds16(pA + inv0, d0);
    gld_lds16(pM + inv1, d0 + 1024);
    gld_lds16(pB + inv2, d0 + 2048);
  }

#pragma unroll 1
  for (int t = 0; t < TT; ++t) {
    int rem = TT - 1 - t;
    if (rem >= 2)
      asm volatile("s_waitcnt vmcnt(6) lgkmcnt(0)" ::: "memory");
    else if (rem == 1)
      asm volatile("s_waitcnt vmcnt(3) lgkmcnt(0)" ::: "memory");
    else
      asm volatile("s_waitcnt vmcnt(0) lgkmcnt(0)" ::: "memory");
    __builtin_amdgcn_s_barrier();
    __builtin_amdgcn_sched_barrier(0);

    const int slot = t & 3, cur = t & 1, nxt = cur ^ 1;
    if (t + 3 < TT) {
      int tokA = xtA[t + 3], tokB = xtB[t + 3];
      const char* pA = tbl + (unsigned)tokA * 1536u;
      const char* pB = tbl + (unsigned)tokB * 1536u;
      const char* pM = (lane < 32) ? pA : pB;
      char* d0 = smem + ((t + 3) & 3) * 24576 + w * 3072;
      gld_lds16(pA + inv0, d0);
      gld_lds16(pM + inv1, d0 + 1024);
      gld_lds16(pB + inv2, d0 + 2048);
    }

    const char* gtile = smem + slot * 24576;

    // acc init: r/z from gi (biases prefolded), n from b_hh_n.
    float4_ acc[2][3];
#pragma unroll
    for (int i = 0; i < 2; ++i) {
#pragma unroll
      for (int q = 0; q < 2; ++q) {
        int byte8 = gi_byte(bl, 32 * (w + 8 * i + 16 * q) + 8 * kg);
        ushort4_ v = *(const ushort4_*)(gtile + byte8);
#pragma unroll
        for (int r = 0; r < 4; ++r) acc[i][q][r] = b2f(v[r]);
      }
      acc[i][2] = bhn[i];
    }

    // gh += W_hh * h
#pragma unroll
    for (int kt = 0; kt < 8; ++kt) {
      int byteoff = ((bl * 512) + kt * 64 + kg * 16) ^ ((bl & 7) << 4);
      short8 bf = *(const short8*)(smem + HB + cur * 8192 + byteoff);
#pragma unroll
      for (int i = 0; i < 2; ++i)
#pragma unroll
        for (int q = 0; q < 3; ++q)
          acc[i][q] = __builtin_amdgcn_mfma_f32_16x16x32_bf16(wf[i][q][kt], bf, acc[i][q], 0, 0, 0);
    }

    // gates + h update, write h_{t+1} to other buffer.
#pragma unroll
    for (int i = 0; i < 2; ++i) {
      int byte8n = gi_byte(bl, 32 * (32 + w + 8 * i) + 8 * kg);
      ushort4_ gv = *(const ushort4_*)(gtile + byte8n);
#pragma unroll
      for (int r = 0; r < 4; ++r) {
        float rr = __builtin_amdgcn_rcpf(1.f + __expf(-acc[i][0][r]));
        float zz = __builtin_amdgcn_rcpf(1.f + __expf(-acc[i][1][r]));
        float y = b2f(gv[r]) + rr * acc[i][2][r];
        float nn = 1.f - 2.f * __builtin_amdgcn_rcpf(1.f + __expf(2.f * y));
        hreg[i][r] = (1.f - zz) * nn + zz * hreg[i][r];
      }
      int byte0 = (bl * 512 + ((w + 8 * i) * 16 + kg * 4) * 2) ^ ((bl & 7) << 4);
      uint2_ hv;
      hv.x = (unsigned)f2b(hreg[i][0]) | ((unsigned)f2b(hreg[i][1]) << 16);
      hv.y = (unsigned)f2b(hreg[i][2]) | ((unsigned)f2b(hreg[i][3]) << 16);
      *(uint2_*)(smem + HB + nxt * 8192 + byte0) = hv;
    }
  }

#pragma unroll
  for (int i = 0; i < 2; ++i) {
    float4_ v = {hreg[i][0], hreg[i][1], hreg[i][2], hreg[i][3]};
    *(float4_*)&out[(size_t)(b0 + bl) * HID + (w + 8 * i) * 16 + kg * 4] = v;
  }
}

extern "C" void kernel_launch(void* const* d_in, const int* in_sizes, int n_in,
                              void* d_out, int out_size, void* d_ws, size_t ws_size,
                              hipStream_t stream) {
  const int* x = (const int*)d_in[0];
  const float* emb = (const float*)d_in[1];
  const float* Wih = (const float*)d_in[2];
  const float* Whh = (const float*)d_in[3];
  const float* bih = (const float*)d_in[4];
  const float* bhh = (const float*)d_in[5];
  float* out = (float*)d_out;

  char* ws = (char*)d_ws;
  ushort_t* emb16 = (ushort_t*)ws;                 // 8,192,000 B
  ushort_t* Wih16 = (ushort_t*)(ws + 8192000);     //   196,608 B
  ushort_t* Whh16 = (ushort_t*)(ws + 8388608);     //   393,216 B
  char* tbl = ws + 8781824;                        // 49,152,000 B token->gi table

  cvt_bf16_k<<<1024, 256, 0, stream>>>(emb, emb16, (VOCAB * EMB) / 4);
  cvt_bf16_k<<<96, 256, 0, stream>>>(Wih, Wih16, (G3 * EMB) / 4);
  cvt_bf16_k<<<192, 256, 0, stream>>>(Whh, Whh16, (G3 * HID) / 4);
  tbl_gemm<<<2000, 256, 0, stream>>>(emb16, Wih16, bih, bhh, tbl);
  gru_rec<<<32, 512, 0, stream>>>(Whh16, tbl, bhh, x, out);
}